// Round 2
// baseline (9821.980 us; speedup 1.0000x reference)
//
#include <hip/hip_runtime.h>
#include <hip/hip_cooperative_groups.h>
#include <stdint.h>

#define T_STEPS 128
#define BATCH   64
#define EMBED   256
#define HIDDEN  512
#define VOCAB   10000
#define M_ROWS  (T_STEPS*BATCH)   // 8192
#define NGATE   (4*HIDDEN)        // 2048

typedef __attribute__((ext_vector_type(4))) float  f32x4;
typedef __attribute__((ext_vector_type(4))) int    i32x4;
typedef __attribute__((ext_vector_type(8))) __bf16 bf16x8;

static __device__ __forceinline__ unsigned short f32_to_bf16(float f) {
    union { float f; uint32_t u; } v; v.f = f;
    uint32_t u = v.u;
    return (unsigned short)((u + 0x7FFFu + ((u >> 16) & 1u)) >> 16);  // RNE
}

// ---------------------------------------------------------------------------
// W [512][10000] f32  ->  Wt [10000][512] bf16   (tiled transpose + convert)
// ---------------------------------------------------------------------------
__global__ void wt_convert(const float* __restrict__ W, unsigned short* __restrict__ Wt) {
    __shared__ float tile[32][33];
    int n0 = blockIdx.x * 32;
    int k0 = blockIdx.y * 32;
    int tx = threadIdx.x, ty = threadIdx.y;
    int n = n0 + tx;
    if (n < VOCAB) tile[ty][tx] = W[(size_t)(k0 + ty) * VOCAB + n];
    __syncthreads();
    int nn = n0 + ty;
    if (nn < VOCAB) Wt[(size_t)nn * HIDDEN + k0 + tx] = f32_to_bf16(tile[tx][ty]);
}

// ---------------------------------------------------------------------------
// xg[m][g*512+hc] = embeddings[input_[m]] @ W_xg + b_g   (fp32 tiled GEMM,
// gather fused).  M=8192, N=2048, K=256.  BM=128 BN=64 BK=32, 256 thr.
// ---------------------------------------------------------------------------
__global__ __launch_bounds__(256) void xproj(
    const int* __restrict__ idx, const float* __restrict__ Emb,
    const float* __restrict__ Wxi, const float* __restrict__ Wxf,
    const float* __restrict__ Wxc, const float* __restrict__ Wxo,
    const float* __restrict__ bi,  const float* __restrict__ bf_,
    const float* __restrict__ bc,  const float* __restrict__ bo,
    float* __restrict__ xg)
{
    __shared__ float At[32][132];   // [k][m], padded
    __shared__ float Bt[32][68];    // [k][n], padded
    int cb = blockIdx.x;            // 0..31 (8 col-blocks per gate)
    int rb = blockIdx.y;            // 0..63
    int g  = cb >> 3;
    int hc0 = (cb & 7) * 64;
    const float* Wg = (g == 0) ? Wxi : (g == 1) ? Wxf : (g == 2) ? Wxc : Wxo;
    const float* bg = (g == 0) ? bi  : (g == 1) ? bf_ : (g == 2) ? bc  : bo;
    int m0 = rb * 128;
    int tid = threadIdx.x;
    int tr = tid >> 4, tc = tid & 15;
    float acc[8][4] = {};

    for (int kc = 0; kc < EMBED; kc += 32) {
        // stage A (gathered embedding rows), transposed into At[k][m]
        #pragma unroll
        for (int i = 0; i < 4; ++i) {
            int s = tid + i * 256;            // 0..1023
            int row = s >> 3, k4 = s & 7;
            int er = idx[m0 + row];
            f32x4 v = *reinterpret_cast<const f32x4*>(Emb + (size_t)er * EMBED + kc + k4 * 4);
            #pragma unroll
            for (int j = 0; j < 4; ++j) At[k4 * 4 + j][row] = v[j];
        }
        // stage B
        #pragma unroll
        for (int i = 0; i < 2; ++i) {
            int s = tid + i * 256;            // 0..511
            int k = s >> 4, c4 = s & 15;
            f32x4 v = *reinterpret_cast<const f32x4*>(Wg + (size_t)(kc + k) * HIDDEN + hc0 + c4 * 4);
            *reinterpret_cast<f32x4*>(&Bt[k][c4 * 4]) = v;
        }
        __syncthreads();
        #pragma unroll 8
        for (int k = 0; k < 32; ++k) {
            f32x4 a0 = *reinterpret_cast<const f32x4*>(&At[k][tr * 8]);
            f32x4 a1 = *reinterpret_cast<const f32x4*>(&At[k][tr * 8 + 4]);
            f32x4 b4 = *reinterpret_cast<const f32x4*>(&Bt[k][tc * 4]);
            float av[8] = {a0[0],a0[1],a0[2],a0[3],a1[0],a1[1],a1[2],a1[3]};
            #pragma unroll
            for (int i = 0; i < 8; ++i)
                #pragma unroll
                for (int j = 0; j < 4; ++j)
                    acc[i][j] += av[i] * b4[j];
        }
        __syncthreads();
    }
    f32x4 bb = *reinterpret_cast<const f32x4*>(bg + hc0 + tc * 4);
    #pragma unroll
    for (int i = 0; i < 8; ++i) {
        int row = m0 + tr * 8 + i;
        f32x4 o;
        #pragma unroll
        for (int j = 0; j < 4; ++j) o[j] = acc[i][j] + bb[j];
        *reinterpret_cast<f32x4*>(xg + (size_t)row * NGATE + g * HIDDEN + hc0 + tc * 4) = o;
    }
}

// ---------------------------------------------------------------------------
// Persistent LSTM scan: ONE cooperative kernel, grid.sync() per timestep.
// 256 blocks x 512 threads. Block bx owns b0..b0+7, hc0..hc0+15; K split
// 4-way across tid>>7. c_t lives in a register of the combine threads.
// ---------------------------------------------------------------------------
__global__ __launch_bounds__(512) void lstm_scan(
    const float* __restrict__ xg,
    const float* __restrict__ Whi, const float* __restrict__ Whf,
    const float* __restrict__ Whc, const float* __restrict__ Who,
    float* __restrict__ hs, unsigned short* __restrict__ hsbf,
    float* __restrict__ cbuf)
{
    namespace cg = cooperative_groups;
    cg::grid_group grid = cg::this_grid();
    __shared__ float H[8][516];     // h rows for this block's 8 b's (padded)
    __shared__ float P[512][4];     // per-thread partials
    const int tid = threadIdx.x;
    const int hcl = tid & 15, bl = (tid >> 4) & 7, kh = tid >> 7;   // kh 0..3
    const int bx  = blockIdx.x;
    const int b0  = (bx >> 5) * 8, hc0 = (bx & 31) * 16;
    const int kbase = kh * 128;
    float c_reg = 0.f;

    for (int t = 0; t < T_STEPS; ++t) {
        float p0 = 0.f, p1 = 0.f, p2 = 0.f, p3 = 0.f;
        if (t > 0) {
            const float* hprev = hs + (size_t)(t - 1) * BATCH * HIDDEN;
            #pragma unroll
            for (int i = 0; i < 2; ++i) {
                int s = tid + i * 512;          // 1024 slots: 8 rows x 128 f32x4
                int row = s >> 7, k4 = s & 127;
                f32x4 v = *reinterpret_cast<const f32x4*>(hprev + (size_t)(b0 + row) * HIDDEN + k4 * 4);
                *reinterpret_cast<f32x4*>(&H[row][k4 * 4]) = v;
            }
            __syncthreads();
            int woff = kbase * HIDDEN + hc0 + hcl;
            #pragma unroll 8
            for (int k = 0; k < 128; ++k) {
                float hv = H[bl][kbase + k];
                p0 += hv * Whi[woff];
                p1 += hv * Whf[woff];
                p2 += hv * Whc[woff];
                p3 += hv * Who[woff];
                woff += HIDDEN;
            }
        }
        P[tid][0] = p0; P[tid][1] = p1; P[tid][2] = p2; P[tid][3] = p3;
        __syncthreads();

        if (tid < 128) {
            int b = b0 + ((tid >> 4) & 7), hc = hc0 + (tid & 15);
            const float* xrow = xg + (size_t)(t * BATCH + b) * NGATE;
            float pi = P[tid][0] + P[tid+128][0] + P[tid+256][0] + P[tid+384][0] + xrow[0*HIDDEN + hc];
            float pf = P[tid][1] + P[tid+128][1] + P[tid+256][1] + P[tid+384][1] + xrow[1*HIDDEN + hc];
            float pg = P[tid][2] + P[tid+128][2] + P[tid+256][2] + P[tid+384][2] + xrow[2*HIDDEN + hc];
            float po = P[tid][3] + P[tid+128][3] + P[tid+256][3] + P[tid+384][3] + xrow[3*HIDDEN + hc];
            float i_ = 1.f / (1.f + __expf(-pi));
            float f_ = 1.f / (1.f + __expf(-pf));
            float eg = __expf(2.f * fminf(fmaxf(pg, -15.f), 15.f));
            float g_ = (eg - 1.f) / (eg + 1.f);
            float o_ = 1.f / (1.f + __expf(-po));
            c_reg = f_ * c_reg + i_ * g_;
            float ec = __expf(2.f * fminf(fmaxf(c_reg, -15.f), 15.f));
            float th = (ec - 1.f) / (ec + 1.f);
            float h = o_ * th;
            size_t ho = (size_t)(t * BATCH + b) * HIDDEN + hc;
            hs[ho] = h;
            hsbf[ho] = f32_to_bf16(h);
        }
        __threadfence();
        grid.sync();
    }
    if (tid < 128) {
        int b = b0 + ((tid >> 4) & 7), hc = hc0 + (tid & 15);
        cbuf[(size_t)b * HIDDEN + hc] = c_reg;
    }
}

// ---------------------------------------------------------------------------
// out = hs_bf16 [8192,512] @ W_bf16^T [10000,512] + b   (bf16 MFMA, f32 acc)
// tile 128x80, BK=64, 4 waves, acc[2][5], XOR-swizzled LDS (T2).
// ---------------------------------------------------------------------------
__global__ __launch_bounds__(256) void out_proj(
    const unsigned short* __restrict__ Abf,   // [8192][512]
    const unsigned short* __restrict__ Btbf,  // [10000][512]
    const float* __restrict__ bias,           // [10000]
    float* __restrict__ Cout)                 // [8192][10000] f32
{
    __shared__ __align__(16) char sA[128 * 128];  // 128 rows x 64 bf16
    __shared__ __align__(16) char sB[80 * 128];   // 80 rows x 64 bf16
    int n0 = blockIdx.x * 80;
    int m0 = blockIdx.y * 128;
    int tid = threadIdx.x;
    int w = tid >> 6, lane = tid & 63;
    f32x4 acc[2][5] = {};

    for (int kc = 0; kc < 8; ++kc) {
        int k0 = kc * 64;
        #pragma unroll
        for (int i = 0; i < 4; ++i) {                  // A: 1024 16B slots
            int s = tid + i * 256;
            int row = s >> 3, slot = s & 7;
            i32x4 v = *reinterpret_cast<const i32x4*>(Abf + (size_t)(m0 + row) * HIDDEN + k0 + slot * 8);
            *reinterpret_cast<i32x4*>(sA + row * 128 + ((slot ^ (row & 7)) * 16)) = v;
        }
        #pragma unroll
        for (int i = 0; i < 3; ++i) {                  // B: 640 slots
            int s = tid + i * 256;
            if (s < 640) {
                int row = s >> 3, slot = s & 7;
                i32x4 v = *reinterpret_cast<const i32x4*>(Btbf + (size_t)(n0 + row) * HIDDEN + k0 + slot * 8);
                *reinterpret_cast<i32x4*>(sB + row * 128 + ((slot ^ (row & 7)) * 16)) = v;
            }
        }
        __syncthreads();
        #pragma unroll
        for (int k2 = 0; k2 < 2; ++k2) {
            bf16x8 a[2], b[5];
            #pragma unroll
            for (int rf = 0; rf < 2; ++rf) {
                int row = w * 32 + rf * 16 + (lane & 15);
                int off = (k2 * 64 + (lane >> 4) * 16) ^ ((row & 7) << 4);
                a[rf] = *reinterpret_cast<const bf16x8*>(sA + row * 128 + off);
            }
            #pragma unroll
            for (int cf = 0; cf < 5; ++cf) {
                int row = cf * 16 + (lane & 15);
                int off = (k2 * 64 + (lane >> 4) * 16) ^ ((row & 7) << 4);
                b[cf] = *reinterpret_cast<const bf16x8*>(sB + row * 128 + off);
            }
            #pragma unroll
            for (int rf = 0; rf < 2; ++rf)
                #pragma unroll
                for (int cf = 0; cf < 5; ++cf)
                    acc[rf][cf] = __builtin_amdgcn_mfma_f32_16x16x32_bf16(a[rf], b[cf], acc[rf][cf], 0, 0, 0);
        }
        __syncthreads();
    }
    #pragma unroll
    for (int cf = 0; cf < 5; ++cf) {
        int col = n0 + cf * 16 + (lane & 15);
        float bv = bias[col];
        #pragma unroll
        for (int rf = 0; rf < 2; ++rf)
            #pragma unroll
            for (int r = 0; r < 4; ++r) {
                int row = m0 + w * 32 + rf * 16 + (lane >> 4) * 4 + r;
                Cout[(size_t)row * VOCAB + col] = acc[rf][cf][r] + bv;
            }
    }
}

// ---------------------------------------------------------------------------
__global__ void finalize_hc(const float* __restrict__ hs, const float* __restrict__ c,
                            float* __restrict__ out) {
    int i = blockIdx.x * 256 + threadIdx.x;       // 0..65535
    size_t base = (size_t)M_ROWS * VOCAB;
    if (i < BATCH * HIDDEN)
        out[base + i] = hs[(size_t)(T_STEPS - 1) * BATCH * HIDDEN + i];
    else
        out[base + i] = c[i - BATCH * HIDDEN];
}

extern "C" void kernel_launch(void* const* d_in, const int* in_sizes, int n_in,
                              void* d_out, int out_size, void* d_ws, size_t ws_size,
                              hipStream_t stream) {
    (void)in_sizes; (void)n_in; (void)out_size; (void)ws_size;
    const int*   input_ = (const int*)  d_in[0];
    const float* Emb    = (const float*)d_in[1];
    const float* Wxi    = (const float*)d_in[2];
    const float* Whi    = (const float*)d_in[3];
    const float* bi     = (const float*)d_in[4];
    const float* Wxf    = (const float*)d_in[5];
    const float* Whf    = (const float*)d_in[6];
    const float* bf_    = (const float*)d_in[7];
    const float* Wxc    = (const float*)d_in[8];
    const float* Whc    = (const float*)d_in[9];
    const float* bc     = (const float*)d_in[10];
    const float* Wxo    = (const float*)d_in[11];
    const float* Who    = (const float*)d_in[12];
    const float* bo     = (const float*)d_in[13];
    const float* W      = (const float*)d_in[14];
    const float* b      = (const float*)d_in[15];
    float* out = (float*)d_out;

    char* ws = (char*)d_ws;
    float*          xg   = (float*)         (ws);                    //  67,108,864 B
    float*          hs   = (float*)         (ws +  67108864);        //  16,777,216 B
    unsigned short* hsbf = (unsigned short*)(ws +  83886080);        //   8,388,608 B
    unsigned short* Wtbf = (unsigned short*)(ws +  92274688);        //  10,240,000 B
    float*          cbuf = (float*)         (ws + 102514688);        //     131,072 B

    wt_convert<<<dim3(313, 16), dim3(32, 32), 0, stream>>>(W, Wtbf);
    xproj<<<dim3(32, 64), 256, 0, stream>>>(input_, Emb, Wxi, Wxf, Wxc, Wxo,
                                            bi, bf_, bc, bo, xg);

    {
        const float* xg_c = xg;
        float* hs_p = hs; unsigned short* hsbf_p = hsbf; float* cbuf_p = cbuf;
        void* args[] = { (void*)&xg_c, (void*)&Whi, (void*)&Whf, (void*)&Whc, (void*)&Who,
                         (void*)&hs_p, (void*)&hsbf_p, (void*)&cbuf_p };
        hipLaunchCooperativeKernel((void*)lstm_scan, dim3(256), dim3(512), args, 0, stream);
    }

    out_proj<<<dim3(125, 64), 256, 0, stream>>>(hsbf, Wtbf, b, out);
    finalize_hc<<<256, 256, 0, stream>>>(hs, cbuf, out);
}

// Round 3
// 1388.233 us; speedup vs baseline: 7.0752x; 7.0752x over previous
//
#include <hip/hip_runtime.h>
#include <stdint.h>

#define T_STEPS 128
#define BATCH   64
#define EMBED   256
#define HIDDEN  512
#define VOCAB   10000
#define M_ROWS  (T_STEPS*BATCH)   // 8192
#define NGATE   (4*HIDDEN)        // 2048
#define NBLK    32                // lstm blocks

typedef __attribute__((ext_vector_type(2))) float  f32x2;
typedef __attribute__((ext_vector_type(4))) float  f32x4;
typedef __attribute__((ext_vector_type(4))) int    i32x4;
typedef __attribute__((ext_vector_type(8))) __bf16 bf16x8;

static __device__ __forceinline__ unsigned short f32_to_bf16(float f) {
    union { float f; uint32_t u; } v; v.f = f;
    uint32_t u = v.u;
    return (unsigned short)((u + 0x7FFFu + ((u >> 16) & 1u)) >> 16);  // RNE
}
static __device__ __forceinline__ float sigf(float x) {
    return 1.f / (1.f + __expf(-x));
}
static __device__ __forceinline__ float tanhfast(float x) {
    float e = __expf(2.f * fminf(fmaxf(x, -15.f), 15.f));
    return (e - 1.f) / (e + 1.f);
}

// ---------------------------------------------------------------------------
// W [512][10000] f32  ->  Wt [10000][512] bf16   (tiled transpose + convert)
// ---------------------------------------------------------------------------
__global__ void wt_convert(const float* __restrict__ W, unsigned short* __restrict__ Wt) {
    __shared__ float tile[32][33];
    int n0 = blockIdx.x * 32;
    int k0 = blockIdx.y * 32;
    int tx = threadIdx.x, ty = threadIdx.y;
    int n = n0 + tx;
    if (n < VOCAB) tile[ty][tx] = W[(size_t)(k0 + ty) * VOCAB + n];
    __syncthreads();
    int nn = n0 + ty;
    if (nn < VOCAB) Wt[(size_t)nn * HIDDEN + k0 + tx] = f32_to_bf16(tile[tx][ty]);
}

// ---------------------------------------------------------------------------
// Wh_g [512 k][512 n] f32 -> WhT [4][512 n][512 k] bf16
// ---------------------------------------------------------------------------
__global__ void wh_convert(const float* __restrict__ Whi, const float* __restrict__ Whf,
                           const float* __restrict__ Whc, const float* __restrict__ Who,
                           unsigned short* __restrict__ WhT) {
    __shared__ float tile[32][33];
    int g = blockIdx.z;
    const float* Wg = (g == 0) ? Whi : (g == 1) ? Whf : (g == 2) ? Whc : Who;
    int n0 = blockIdx.x * 32, k0 = blockIdx.y * 32;
    int tx = threadIdx.x, ty = threadIdx.y;
    tile[ty][tx] = Wg[(size_t)(k0 + ty) * HIDDEN + n0 + tx];
    __syncthreads();
    WhT[((size_t)g * HIDDEN + n0 + ty) * HIDDEN + k0 + tx] = f32_to_bf16(tile[tx][ty]);
}

// ---------------------------------------------------------------------------
// xg[m][g*512+hc] = embeddings[input_[m]] @ W_xg + b_g   (fp32 tiled GEMM)
// ---------------------------------------------------------------------------
__global__ __launch_bounds__(256) void xproj(
    const int* __restrict__ idx, const float* __restrict__ Emb,
    const float* __restrict__ Wxi, const float* __restrict__ Wxf,
    const float* __restrict__ Wxc, const float* __restrict__ Wxo,
    const float* __restrict__ bi,  const float* __restrict__ bf_,
    const float* __restrict__ bc,  const float* __restrict__ bo,
    float* __restrict__ xg)
{
    __shared__ float At[32][132];   // [k][m], padded
    __shared__ float Bt[32][68];    // [k][n], padded
    int cb = blockIdx.x;            // 0..31 (8 col-blocks per gate)
    int rb = blockIdx.y;            // 0..63
    int g  = cb >> 3;
    int hc0 = (cb & 7) * 64;
    const float* Wg = (g == 0) ? Wxi : (g == 1) ? Wxf : (g == 2) ? Wxc : Wxo;
    const float* bg = (g == 0) ? bi  : (g == 1) ? bf_ : (g == 2) ? bc  : bo;
    int m0 = rb * 128;
    int tid = threadIdx.x;
    int tr = tid >> 4, tc = tid & 15;
    float acc[8][4] = {};

    for (int kc = 0; kc < EMBED; kc += 32) {
        #pragma unroll
        for (int i = 0; i < 4; ++i) {
            int s = tid + i * 256;            // 0..1023
            int row = s >> 3, k4 = s & 7;
            int er = idx[m0 + row];
            f32x4 v = *reinterpret_cast<const f32x4*>(Emb + (size_t)er * EMBED + kc + k4 * 4);
            #pragma unroll
            for (int j = 0; j < 4; ++j) At[k4 * 4 + j][row] = v[j];
        }
        #pragma unroll
        for (int i = 0; i < 2; ++i) {
            int s = tid + i * 256;            // 0..511
            int k = s >> 4, c4 = s & 15;
            f32x4 v = *reinterpret_cast<const f32x4*>(Wg + (size_t)(kc + k) * HIDDEN + hc0 + c4 * 4);
            *reinterpret_cast<f32x4*>(&Bt[k][c4 * 4]) = v;
        }
        __syncthreads();
        #pragma unroll 8
        for (int k = 0; k < 32; ++k) {
            f32x4 a0 = *reinterpret_cast<const f32x4*>(&At[k][tr * 8]);
            f32x4 a1 = *reinterpret_cast<const f32x4*>(&At[k][tr * 8 + 4]);
            f32x4 b4 = *reinterpret_cast<const f32x4*>(&Bt[k][tc * 4]);
            float av[8] = {a0[0],a0[1],a0[2],a0[3],a1[0],a1[1],a1[2],a1[3]};
            #pragma unroll
            for (int i = 0; i < 8; ++i)
                #pragma unroll
                for (int j = 0; j < 4; ++j)
                    acc[i][j] += av[i] * b4[j];
        }
        __syncthreads();
    }
    f32x4 bb = *reinterpret_cast<const f32x4*>(bg + hc0 + tc * 4);
    #pragma unroll
    for (int i = 0; i < 8; ++i) {
        int row = m0 + tr * 8 + i;
        f32x4 o;
        #pragma unroll
        for (int j = 0; j < 4; ++j) o[j] = acc[i][j] + bb[j];
        *reinterpret_cast<f32x4*>(xg + (size_t)row * NGATE + g * HIDDEN + hc0 + tc * 4) = o;
    }
}

// ---------------------------------------------------------------------------
// Persistent LSTM scan, 32 blocks x 512 threads, hand-rolled IC barrier.
// Block bx owns hc [bx*16, bx*16+16) for all 4 gates, all 64 batch rows.
// Waves (wm 0..1, wg 0..3): preact[wm*32..+32 rows, 16 hc] of gate wg via
// MFMA 16x16x32 bf16; Wh slice lives in registers (preloaded once).
// h exchanged through hbuf (bf16) with AGENT-scope atomics (IC-coherent,
// no fences). Barrier: per-step counter + acquire spin, tid 0 only.
// ---------------------------------------------------------------------------
__global__ __launch_bounds__(512) void lstm_scan(
    const float* __restrict__ xg,
    const unsigned short* __restrict__ WhT,   // [4][512][512] bf16
    unsigned short* hbuf,                     // [64][512] bf16 exchange
    unsigned short* __restrict__ hsbf,        // [128][64][512] bf16
    float* __restrict__ hfin, float* __restrict__ cfin,
    unsigned* bar)                            // [128] counters, pre-zeroed
{
    __shared__ __align__(16) unsigned char hstage[65536];  // 64 x 512 bf16, swizzled
    __shared__ float P_lds[4][64][16];
    const int tid  = threadIdx.x;
    const int bx   = blockIdx.x;        // 0..31
    const int hc0  = bx * 16;
    const int lane = tid & 63, w = tid >> 6;
    const int wm   = w >> 2, wg = w & 3;

    // ---- preload Wh slice: wave (.,wg) lane l: col hc0+(l&15), 8 k per kstep
    bf16x8 breg[16];
    {
        const unsigned short* base =
            WhT + ((size_t)wg * HIDDEN + hc0 + (lane & 15)) * HIDDEN + (lane >> 4) * 8;
        #pragma unroll
        for (int ks = 0; ks < 16; ++ks)
            breg[ks] = *reinterpret_cast<const bf16x8*>(base + ks * 32);
    }

    // ---- update-thread mapping: thread -> (batch, hc pair)
    const int ub  = tid >> 3;          // 0..63
    const int uhp = tid & 7;           // 0..7
    const int uhc = hc0 + uhp * 2;
    float c0 = 0.f, c1 = 0.f;
    f32x2 xv[4];
    {
        const float* xrow = xg + (size_t)ub * NGATE + uhc;
        #pragma unroll
        for (int g = 0; g < 4; ++g)
            xv[g] = *reinterpret_cast<const f32x2*>(xrow + g * HIDDEN);
    }

    for (int t = 0; t < T_STEPS; ++t) {
        f32x4 acc0 = {0.f,0.f,0.f,0.f}, acc1 = {0.f,0.f,0.f,0.f};
        if (t > 0) {
            // stage h_{t-1} (64KB bf16) into LDS via IC-coherent loads, XOR-swizzled
            #pragma unroll
            for (int i = 0; i < 16; ++i) {
                int s = i * 512 + tid;                    // 8B unit index
                unsigned long long v = __hip_atomic_load(
                    reinterpret_cast<unsigned long long*>(hbuf) + s,
                    __ATOMIC_RELAXED, __HIP_MEMORY_SCOPE_AGENT);
                int row = s >> 7;                         // 128 x 8B per row
                int sl  = (s & 127) >> 1;                 // 16B slot 0..63
                int off = row * 1024 + ((sl ^ (row & 7)) << 4) + ((s & 1) << 3);
                *reinterpret_cast<unsigned long long*>(hstage + off) = v;
            }
            __syncthreads();
            const int r0 = wm * 32 + (lane & 15);
            const int r1 = r0 + 16;
            #pragma unroll
            for (int ks = 0; ks < 16; ++ks) {
                int sl = ks * 4 + (lane >> 4);
                bf16x8 a0 = *reinterpret_cast<const bf16x8*>(
                    hstage + r0 * 1024 + ((sl ^ (r0 & 7)) << 4));
                bf16x8 a1 = *reinterpret_cast<const bf16x8*>(
                    hstage + r1 * 1024 + ((sl ^ (r1 & 7)) << 4));
                acc0 = __builtin_amdgcn_mfma_f32_16x16x32_bf16(a0, breg[ks], acc0, 0, 0, 0);
                acc1 = __builtin_amdgcn_mfma_f32_16x16x32_bf16(a1, breg[ks], acc1, 0, 0, 0);
            }
        }
        // ---- exchange preacts via LDS (C layout: col=lane&15, row=(lane>>4)*4+r)
        {
            int colr = lane & 15, rowb = (lane >> 4) * 4;
            #pragma unroll
            for (int r = 0; r < 4; ++r) {
                P_lds[wg][wm * 32 + rowb + r][colr]      = acc0[r];
                P_lds[wg][wm * 32 + 16 + rowb + r][colr] = acc1[r];
            }
        }
        __syncthreads();
        // ---- cell update: 2 (b,hc) per thread
        {
            int hp2 = uhp * 2;
            float pi0 = P_lds[0][ub][hp2] + xv[0][0], pi1 = P_lds[0][ub][hp2+1] + xv[0][1];
            float pf0 = P_lds[1][ub][hp2] + xv[1][0], pf1 = P_lds[1][ub][hp2+1] + xv[1][1];
            float pg0 = P_lds[2][ub][hp2] + xv[2][0], pg1 = P_lds[2][ub][hp2+1] + xv[2][1];
            float po0 = P_lds[3][ub][hp2] + xv[3][0], po1 = P_lds[3][ub][hp2+1] + xv[3][1];
            float i0 = sigf(pi0), i1 = sigf(pi1);
            float f0 = sigf(pf0), f1 = sigf(pf1);
            float g0 = tanhfast(pg0), g1 = tanhfast(pg1);
            float o0 = sigf(po0), o1 = sigf(po1);
            c0 = f0 * c0 + i0 * g0;
            c1 = f1 * c1 + i1 * g1;
            float h0 = o0 * tanhfast(c0);
            float h1 = o1 * tanhfast(c1);
            unsigned hp = ((unsigned)f32_to_bf16(h1) << 16) | (unsigned)f32_to_bf16(h0);
            // h exchange (IC-coherent store) + history (regular store)
            __hip_atomic_store(reinterpret_cast<unsigned*>(hbuf) + ub * 256 + (uhc >> 1),
                               hp, __ATOMIC_RELAXED, __HIP_MEMORY_SCOPE_AGENT);
            reinterpret_cast<unsigned*>(hsbf)[(size_t)(t * BATCH + ub) * 256 + (uhc >> 1)] = hp;
            if (t == T_STEPS - 1) {
                f32x2 hv = { h0, h1 };
                *reinterpret_cast<f32x2*>(hfin + (size_t)ub * HIDDEN + uhc) = hv;
            }
            // prefetch next step's x-gate row (independent of barrier)
            if (t + 1 < T_STEPS) {
                const float* xrow = xg + (size_t)((t + 1) * BATCH + ub) * NGATE + uhc;
                #pragma unroll
                for (int g = 0; g < 4; ++g)
                    xv[g] = *reinterpret_cast<const f32x2*>(xrow + g * HIDDEN);
            }
        }
        // ---- grid barrier (skip after last step)
        if (t < T_STEPS - 1) {
            __syncthreads();   // drains every thread's h store (vmcnt(0) before s_barrier)
            if (tid == 0) {
                __hip_atomic_fetch_add(bar + t, 1u, __ATOMIC_ACQ_REL, __HIP_MEMORY_SCOPE_AGENT);
                while (__hip_atomic_load(bar + t, __ATOMIC_ACQUIRE, __HIP_MEMORY_SCOPE_AGENT) < (unsigned)NBLK)
                    __builtin_amdgcn_s_sleep(2);
            }
            __syncthreads();
        }
    }
    // ---- final c
    {
        f32x2 cv = { c0, c1 };
        *reinterpret_cast<f32x2*>(cfin + (size_t)ub * HIDDEN + uhc) = cv;
    }
}

// ---------------------------------------------------------------------------
// out = hs_bf16 [8192,512] @ W_bf16^T [10000,512] + b   (bf16 MFMA, f32 acc)
// ---------------------------------------------------------------------------
__global__ __launch_bounds__(256) void out_proj(
    const unsigned short* __restrict__ Abf,   // [8192][512]
    const unsigned short* __restrict__ Btbf,  // [10000][512]
    const float* __restrict__ bias,           // [10000]
    float* __restrict__ Cout)                 // [8192][10000] f32
{
    __shared__ __align__(16) char sA[128 * 128];  // 128 rows x 64 bf16
    __shared__ __align__(16) char sB[80 * 128];   // 80 rows x 64 bf16
    int n0 = blockIdx.x * 80;
    int m0 = blockIdx.y * 128;
    int tid = threadIdx.x;
    int w = tid >> 6, lane = tid & 63;
    f32x4 acc[2][5] = {};

    for (int kc = 0; kc < 8; ++kc) {
        int k0 = kc * 64;
        #pragma unroll
        for (int i = 0; i < 4; ++i) {                  // A: 1024 16B slots
            int s = tid + i * 256;
            int row = s >> 3, slot = s & 7;
            i32x4 v = *reinterpret_cast<const i32x4*>(Abf + (size_t)(m0 + row) * HIDDEN + k0 + slot * 8);
            *reinterpret_cast<i32x4*>(sA + row * 128 + ((slot ^ (row & 7)) * 16)) = v;
        }
        #pragma unroll
        for (int i = 0; i < 3; ++i) {                  // B: 640 slots
            int s = tid + i * 256;
            if (s < 640) {
                int row = s >> 3, slot = s & 7;
                i32x4 v = *reinterpret_cast<const i32x4*>(Btbf + (size_t)(n0 + row) * HIDDEN + k0 + slot * 8);
                *reinterpret_cast<i32x4*>(sB + row * 128 + ((slot ^ (row & 7)) * 16)) = v;
            }
        }
        __syncthreads();
        #pragma unroll
        for (int k2 = 0; k2 < 2; ++k2) {
            bf16x8 a[2], b[5];
            #pragma unroll
            for (int rf = 0; rf < 2; ++rf) {
                int row = w * 32 + rf * 16 + (lane & 15);
                int off = (k2 * 64 + (lane >> 4) * 16) ^ ((row & 7) << 4);
                a[rf] = *reinterpret_cast<const bf16x8*>(sA + row * 128 + off);
            }
            #pragma unroll
            for (int cf = 0; cf < 5; ++cf) {
                int row = cf * 16 + (lane & 15);
                int off = (k2 * 64 + (lane >> 4) * 16) ^ ((row & 7) << 4);
                b[cf] = *reinterpret_cast<const bf16x8*>(sB + row * 128 + off);
            }
            #pragma unroll
            for (int rf = 0; rf < 2; ++rf)
                #pragma unroll
                for (int cf = 0; cf < 5; ++cf)
                    acc[rf][cf] = __builtin_amdgcn_mfma_f32_16x16x32_bf16(a[rf], b[cf], acc[rf][cf], 0, 0, 0);
        }
        __syncthreads();
    }
    #pragma unroll
    for (int cf = 0; cf < 5; ++cf) {
        int col = n0 + cf * 16 + (lane & 15);
        float bv = bias[col];
        #pragma unroll
        for (int rf = 0; rf < 2; ++rf)
            #pragma unroll
            for (int r = 0; r < 4; ++r) {
                int row = m0 + w * 32 + rf * 16 + (lane >> 4) * 4 + r;
                Cout[(size_t)row * VOCAB + col] = acc[rf][cf][r] + bv;
            }
    }
}

// ---------------------------------------------------------------------------
__global__ void finalize_hc(const float* __restrict__ hfin, const float* __restrict__ cfin,
                            float* __restrict__ out) {
    int i = blockIdx.x * 256 + threadIdx.x;       // 0..65535
    size_t base = (size_t)M_ROWS * VOCAB;
    if (i < BATCH * HIDDEN)
        out[base + i] = hfin[i];
    else
        out[base + i] = cfin[i - BATCH * HIDDEN];
}

extern "C" void kernel_launch(void* const* d_in, const int* in_sizes, int n_in,
                              void* d_out, int out_size, void* d_ws, size_t ws_size,
                              hipStream_t stream) {
    (void)in_sizes; (void)n_in; (void)out_size; (void)ws_size;
    const int*   input_ = (const int*)  d_in[0];
    const float* Emb    = (const float*)d_in[1];
    const float* Wxi    = (const float*)d_in[2];
    const float* Whi    = (const float*)d_in[3];
    const float* bi     = (const float*)d_in[4];
    const float* Wxf    = (const float*)d_in[5];
    const float* Whf    = (const float*)d_in[6];
    const float* bf_    = (const float*)d_in[7];
    const float* Wxc    = (const float*)d_in[8];
    const float* Whc    = (const float*)d_in[9];
    const float* bc     = (const float*)d_in[10];
    const float* Wxo    = (const float*)d_in[11];
    const float* Who    = (const float*)d_in[12];
    const float* bo     = (const float*)d_in[13];
    const float* W      = (const float*)d_in[14];
    const float* b      = (const float*)d_in[15];
    float* out = (float*)d_out;

    char* ws = (char*)d_ws;
    float*          xg   = (float*)         (ws);                 // 67,108,864
    unsigned short* hsbf = (unsigned short*)(ws +  67108864);     //  8,388,608
    unsigned short* Wtbf = (unsigned short*)(ws +  75497472);     // 10,240,000
    unsigned short* WhT  = (unsigned short*)(ws +  85737472);     //  2,097,152
    unsigned short* hbuf = (unsigned short*)(ws +  87834624);     //     65,536
    float*          hfin = (float*)         (ws +  87900160);     //    131,072
    float*          cbuf = (float*)         (ws +  88031232);     //    131,072
    unsigned*       bar  = (unsigned*)      (ws +  88162304);     //        512

    wt_convert<<<dim3(313, 16), dim3(32, 32), 0, stream>>>(W, Wtbf);
    wh_convert<<<dim3(16, 16, 4), dim3(32, 32), 0, stream>>>(Whi, Whf, Whc, Who, WhT);
    xproj<<<dim3(32, 64), 256, 0, stream>>>(input_, Emb, Wxi, Wxf, Wxc, Wxo,
                                            bi, bf_, bc, bo, xg);
    hipMemsetAsync(bar, 0, 512, stream);

    {
        const float* xg_c = xg;
        const unsigned short* WhT_c = WhT;
        unsigned short* hbuf_p = hbuf; unsigned short* hsbf_p = hsbf;
        float* hfin_p = hfin; float* cbuf_p = cbuf; unsigned* bar_p = bar;
        void* args[] = { (void*)&xg_c, (void*)&WhT_c, (void*)&hbuf_p, (void*)&hsbf_p,
                         (void*)&hfin_p, (void*)&cbuf_p, (void*)&bar_p };
        hipLaunchCooperativeKernel((void*)lstm_scan, dim3(NBLK), dim3(512), args, 0, stream);
    }

    out_proj<<<dim3(125, 64), 256, 0, stream>>>(hsbf, Wtbf, b, out);
    finalize_hc<<<256, 256, 0, stream>>>(hfin, cbuf, out);
}

// Round 4
// 903.622 us; speedup vs baseline: 10.8696x; 1.5363x over previous
//
#include <hip/hip_runtime.h>
#include <stdint.h>

#define T_STEPS 128
#define BATCH   64
#define EMBED   256
#define HIDDEN  512
#define VOCAB   10000
#define M_ROWS  (T_STEPS*BATCH)   // 8192
#define NGATE   (4*HIDDEN)        // 2048
#define NBLK    32                // lstm blocks

typedef __attribute__((ext_vector_type(2))) float  f32x2;
typedef __attribute__((ext_vector_type(4))) float  f32x4;
typedef __attribute__((ext_vector_type(4))) int    i32x4;
typedef __attribute__((ext_vector_type(8))) __bf16 bf16x8;

static __device__ __forceinline__ unsigned short f32_to_bf16(float f) {
    union { float f; uint32_t u; } v; v.f = f;
    uint32_t u = v.u;
    return (unsigned short)((u + 0x7FFFu + ((u >> 16) & 1u)) >> 16);  // RNE
}
static __device__ __forceinline__ float sigf(float x) {
    return 1.f / (1.f + __expf(-x));
}
static __device__ __forceinline__ float tanhfast(float x) {
    float e = __expf(2.f * fminf(fmaxf(x, -15.f), 15.f));
    return (e - 1.f) / (e + 1.f);
}

// ---------------------------------------------------------------------------
// W [512][10000] f32  ->  Wt [10000][512] bf16   (tiled transpose + convert)
// ---------------------------------------------------------------------------
__global__ void wt_convert(const float* __restrict__ W, unsigned short* __restrict__ Wt) {
    __shared__ float tile[32][33];
    int n0 = blockIdx.x * 32;
    int k0 = blockIdx.y * 32;
    int tx = threadIdx.x, ty = threadIdx.y;
    int n = n0 + tx;
    if (n < VOCAB) tile[ty][tx] = W[(size_t)(k0 + ty) * VOCAB + n];
    __syncthreads();
    int nn = n0 + ty;
    if (nn < VOCAB) Wt[(size_t)nn * HIDDEN + k0 + tx] = f32_to_bf16(tile[tx][ty]);
}

// ---------------------------------------------------------------------------
// Wh_g [512 k][512 n] f32 -> WhT [4][512 n][512 k] bf16
// ---------------------------------------------------------------------------
__global__ void wh_convert(const float* __restrict__ Whi, const float* __restrict__ Whf,
                           const float* __restrict__ Whc, const float* __restrict__ Who,
                           unsigned short* __restrict__ WhT) {
    __shared__ float tile[32][33];
    int g = blockIdx.z;
    const float* Wg = (g == 0) ? Whi : (g == 1) ? Whf : (g == 2) ? Whc : Who;
    int n0 = blockIdx.x * 32, k0 = blockIdx.y * 32;
    int tx = threadIdx.x, ty = threadIdx.y;
    tile[ty][tx] = Wg[(size_t)(k0 + ty) * HIDDEN + n0 + tx];
    __syncthreads();
    WhT[((size_t)g * HIDDEN + n0 + ty) * HIDDEN + k0 + tx] = f32_to_bf16(tile[tx][ty]);
}

// ---------------------------------------------------------------------------
// xg[m][g*512+hc] = embeddings[input_[m]] @ W_xg + b_g   (fp32 tiled GEMM)
// ---------------------------------------------------------------------------
__global__ __launch_bounds__(256) void xproj(
    const int* __restrict__ idx, const float* __restrict__ Emb,
    const float* __restrict__ Wxi, const float* __restrict__ Wxf,
    const float* __restrict__ Wxc, const float* __restrict__ Wxo,
    const float* __restrict__ bi,  const float* __restrict__ bf_,
    const float* __restrict__ bc,  const float* __restrict__ bo,
    float* __restrict__ xg)
{
    __shared__ float At[32][132];   // [k][m], padded
    __shared__ float Bt[32][68];    // [k][n], padded
    int cb = blockIdx.x;            // 0..31 (8 col-blocks per gate)
    int rb = blockIdx.y;            // 0..63
    int g  = cb >> 3;
    int hc0 = (cb & 7) * 64;
    const float* Wg = (g == 0) ? Wxi : (g == 1) ? Wxf : (g == 2) ? Wxc : Wxo;
    const float* bg = (g == 0) ? bi  : (g == 1) ? bf_ : (g == 2) ? bc  : bo;
    int m0 = rb * 128;
    int tid = threadIdx.x;
    int tr = tid >> 4, tc = tid & 15;
    float acc[8][4] = {};

    for (int kc = 0; kc < EMBED; kc += 32) {
        #pragma unroll
        for (int i = 0; i < 4; ++i) {
            int s = tid + i * 256;            // 0..1023
            int row = s >> 3, k4 = s & 7;
            int er = idx[m0 + row];
            f32x4 v = *reinterpret_cast<const f32x4*>(Emb + (size_t)er * EMBED + kc + k4 * 4);
            #pragma unroll
            for (int j = 0; j < 4; ++j) At[k4 * 4 + j][row] = v[j];
        }
        #pragma unroll
        for (int i = 0; i < 2; ++i) {
            int s = tid + i * 256;            // 0..511
            int k = s >> 4, c4 = s & 15;
            f32x4 v = *reinterpret_cast<const f32x4*>(Wg + (size_t)(kc + k) * HIDDEN + hc0 + c4 * 4);
            *reinterpret_cast<f32x4*>(&Bt[k][c4 * 4]) = v;
        }
        __syncthreads();
        #pragma unroll 8
        for (int k = 0; k < 32; ++k) {
            f32x4 a0 = *reinterpret_cast<const f32x4*>(&At[k][tr * 8]);
            f32x4 a1 = *reinterpret_cast<const f32x4*>(&At[k][tr * 8 + 4]);
            f32x4 b4 = *reinterpret_cast<const f32x4*>(&Bt[k][tc * 4]);
            float av[8] = {a0[0],a0[1],a0[2],a0[3],a1[0],a1[1],a1[2],a1[3]};
            #pragma unroll
            for (int i = 0; i < 8; ++i)
                #pragma unroll
                for (int j = 0; j < 4; ++j)
                    acc[i][j] += av[i] * b4[j];
        }
        __syncthreads();
    }
    f32x4 bb = *reinterpret_cast<const f32x4*>(bg + hc0 + tc * 4);
    #pragma unroll
    for (int i = 0; i < 8; ++i) {
        int row = m0 + tr * 8 + i;
        f32x4 o;
        #pragma unroll
        for (int j = 0; j < 4; ++j) o[j] = acc[i][j] + bb[j];
        *reinterpret_cast<f32x4*>(xg + (size_t)row * NGATE + g * HIDDEN + hc0 + tc * 4) = o;
    }
}

// ---------------------------------------------------------------------------
// Persistent LSTM scan, 32 blocks x 512 threads.
// h exchange: raw sc0/sc1 global loads/stores (IC-coherent, fully pipelined).
// Barrier: RELAXED atomics only (no L2 invalidate); visibility via explicit
// vmcnt(0) drains of the sc-bypassing data ops.
// ---------------------------------------------------------------------------
__global__ __launch_bounds__(512) void lstm_scan(
    const float* __restrict__ xg,
    const unsigned short* __restrict__ WhT,   // [4][512][512] bf16
    unsigned short* hbuf,                     // [64][512] bf16 exchange
    unsigned short* __restrict__ hsbf,        // [128][64][512] bf16
    float* __restrict__ hfin, float* __restrict__ cfin,
    unsigned* bar)                            // [128] counters, pre-zeroed
{
    __shared__ __align__(16) unsigned char hstage[65536];  // 64 x 512 bf16, swizzled
    __shared__ float P_lds[4][64][17];                     // padded (bank)
    const int tid  = threadIdx.x;
    const int bx   = blockIdx.x;        // 0..31
    const int hc0  = bx * 16;
    const int lane = tid & 63, w = tid >> 6;
    const int wm   = w >> 2, wg = w & 3;

    // ---- preload Wh slice: wave (.,wg) lane l: col hc0+(l&15), 8 k per kstep
    bf16x8 breg[16];
    {
        const unsigned short* base =
            WhT + ((size_t)wg * HIDDEN + hc0 + (lane & 15)) * HIDDEN + (lane >> 4) * 8;
        #pragma unroll
        for (int ks = 0; ks < 16; ++ks)
            breg[ks] = *reinterpret_cast<const bf16x8*>(base + ks * 32);
    }

    // ---- update-thread mapping: thread -> (batch, hc pair)
    const int ub  = tid >> 3;          // 0..63
    const int uhp = tid & 7;           // 0..7
    const int uhc = hc0 + uhp * 2;
    float c0 = 0.f, c1 = 0.f;
    f32x2 xv[4];
    {
        const float* xrow = xg + (size_t)ub * NGATE + uhc;
        #pragma unroll
        for (int g = 0; g < 4; ++g)
            xv[g] = *reinterpret_cast<const f32x2*>(xrow + g * HIDDEN);
    }

    const char* hb = (const char*)hbuf;

    for (int t = 0; t < T_STEPS; ++t) {
        f32x4 acc0 = {0.f,0.f,0.f,0.f}, acc1 = {0.f,0.f,0.f,0.f};
        if (t > 0) {
            // stage h_{t-1} (64KB) into LDS: 8x16B per thread, sc0/sc1 raw
            // loads (bypass L1/L2 -> IC-coherent), single drain, then LDS.
            i32x4 r0, r1, r2, r3, r4, r5, r6, r7;
#define LDIC(R, I) asm volatile("global_load_dwordx4 %0, %1, off sc0 sc1" \
        : "=v"(R) : "v"(hb + (size_t)((I) * 512 + tid) * 16));
            LDIC(r0, 0) LDIC(r1, 1) LDIC(r2, 2) LDIC(r3, 3)
            LDIC(r4, 4) LDIC(r5, 5) LDIC(r6, 6) LDIC(r7, 7)
#undef LDIC
            asm volatile("s_waitcnt vmcnt(0)" ::: "memory");
            __builtin_amdgcn_sched_barrier(0);
#define STLDS(R, I) { int s16 = (I) * 512 + tid; int row = s16 >> 6, sl = s16 & 63; \
        *reinterpret_cast<i32x4*>(hstage + row * 1024 + ((sl ^ (row & 7)) << 4)) = R; }
            STLDS(r0, 0) STLDS(r1, 1) STLDS(r2, 2) STLDS(r3, 3)
            STLDS(r4, 4) STLDS(r5, 5) STLDS(r6, 6) STLDS(r7, 7)
#undef STLDS
            __syncthreads();
            const int r0r = wm * 32 + (lane & 15);
            const int r1r = r0r + 16;
            #pragma unroll
            for (int ks = 0; ks < 16; ++ks) {
                int sl = ks * 4 + (lane >> 4);
                bf16x8 a0 = *reinterpret_cast<const bf16x8*>(
                    hstage + r0r * 1024 + ((sl ^ (r0r & 7)) << 4));
                bf16x8 a1 = *reinterpret_cast<const bf16x8*>(
                    hstage + r1r * 1024 + ((sl ^ (r1r & 7)) << 4));
                acc0 = __builtin_amdgcn_mfma_f32_16x16x32_bf16(a0, breg[ks], acc0, 0, 0, 0);
                acc1 = __builtin_amdgcn_mfma_f32_16x16x32_bf16(a1, breg[ks], acc1, 0, 0, 0);
            }
        }
        // ---- exchange preacts via LDS (C layout: col=lane&15, row=(lane>>4)*4+r)
        {
            int colr = lane & 15, rowb = (lane >> 4) * 4;
            #pragma unroll
            for (int r = 0; r < 4; ++r) {
                P_lds[wg][wm * 32 + rowb + r][colr]      = acc0[r];
                P_lds[wg][wm * 32 + 16 + rowb + r][colr] = acc1[r];
            }
        }
        __syncthreads();
        // ---- cell update: 2 (b,hc) per thread
        {
            int hp2 = uhp * 2;
            float pi0 = P_lds[0][ub][hp2] + xv[0][0], pi1 = P_lds[0][ub][hp2+1] + xv[0][1];
            float pf0 = P_lds[1][ub][hp2] + xv[1][0], pf1 = P_lds[1][ub][hp2+1] + xv[1][1];
            float pg0 = P_lds[2][ub][hp2] + xv[2][0], pg1 = P_lds[2][ub][hp2+1] + xv[2][1];
            float po0 = P_lds[3][ub][hp2] + xv[3][0], po1 = P_lds[3][ub][hp2+1] + xv[3][1];
            float i0 = sigf(pi0), i1 = sigf(pi1);
            float f0 = sigf(pf0), f1 = sigf(pf1);
            float g0 = tanhfast(pg0), g1 = tanhfast(pg1);
            float o0 = sigf(po0), o1 = sigf(po1);
            c0 = f0 * c0 + i0 * g0;
            c1 = f1 * c1 + i1 * g1;
            float h0 = o0 * tanhfast(c0);
            float h1 = o1 * tanhfast(c1);
            unsigned hp = ((unsigned)f32_to_bf16(h1) << 16) | (unsigned)f32_to_bf16(h0);
            // h exchange: raw sc0/sc1 store straight to IC
            {
                const char* dst = hb + ((size_t)ub * 256 + (uhc >> 1)) * 4;
                asm volatile("global_store_dword %0, %1, off sc0 sc1"
                             :: "v"(dst), "v"(hp) : "memory");
            }
            reinterpret_cast<unsigned*>(hsbf)[(size_t)(t * BATCH + ub) * 256 + (uhc >> 1)] = hp;
            if (t == T_STEPS - 1) {
                f32x2 hv = { h0, h1 };
                *reinterpret_cast<f32x2*>(hfin + (size_t)ub * HIDDEN + uhc) = hv;
            }
            // prefetch next step's x-gate row (overlaps barrier wait)
            if (t + 1 < T_STEPS) {
                const float* xrow = xg + (size_t)((t + 1) * BATCH + ub) * NGATE + uhc;
                #pragma unroll
                for (int g = 0; g < 4; ++g)
                    xv[g] = *reinterpret_cast<const f32x2*>(xrow + g * HIDDEN);
            }
        }
        // ---- grid barrier (skip after last step); RELAXED atomics only
        if (t < T_STEPS - 1) {
            asm volatile("s_waitcnt vmcnt(0)" ::: "memory");  // drain h stores
            __syncthreads();
            if (tid == 0) {
                __hip_atomic_fetch_add(bar + t, 1u, __ATOMIC_RELAXED, __HIP_MEMORY_SCOPE_AGENT);
                while (__hip_atomic_load(bar + t, __ATOMIC_RELAXED, __HIP_MEMORY_SCOPE_AGENT) < (unsigned)NBLK)
                    __builtin_amdgcn_s_sleep(2);
            }
            __syncthreads();
        }
    }
    // ---- final c
    {
        f32x2 cv = { c0, c1 };
        *reinterpret_cast<f32x2*>(cfin + (size_t)ub * HIDDEN + uhc) = cv;
    }
}

// ---------------------------------------------------------------------------
// out = hs_bf16 [8192,512] @ W_bf16^T [10000,512] + b   (bf16 MFMA, f32 acc)
// ---------------------------------------------------------------------------
__global__ __launch_bounds__(256) void out_proj(
    const unsigned short* __restrict__ Abf,   // [8192][512]
    const unsigned short* __restrict__ Btbf,  // [10000][512]
    const float* __restrict__ bias,           // [10000]
    float* __restrict__ Cout)                 // [8192][10000] f32
{
    __shared__ __align__(16) char sA[128 * 128];  // 128 rows x 64 bf16
    __shared__ __align__(16) char sB[80 * 128];   // 80 rows x 64 bf16
    int n0 = blockIdx.x * 80;
    int m0 = blockIdx.y * 128;
    int tid = threadIdx.x;
    int w = tid >> 6, lane = tid & 63;
    f32x4 acc[2][5] = {};

    for (int kc = 0; kc < 8; ++kc) {
        int k0 = kc * 64;
        #pragma unroll
        for (int i = 0; i < 4; ++i) {                  // A: 1024 16B slots
            int s = tid + i * 256;
            int row = s >> 3, slot = s & 7;
            i32x4 v = *reinterpret_cast<const i32x4*>(Abf + (size_t)(m0 + row) * HIDDEN + k0 + slot * 8);
            *reinterpret_cast<i32x4*>(sA + row * 128 + ((slot ^ (row & 7)) * 16)) = v;
        }
        #pragma unroll
        for (int i = 0; i < 3; ++i) {                  // B: 640 slots
            int s = tid + i * 256;
            if (s < 640) {
                int row = s >> 3, slot = s & 7;
                i32x4 v = *reinterpret_cast<const i32x4*>(Btbf + (size_t)(n0 + row) * HIDDEN + k0 + slot * 8);
                *reinterpret_cast<i32x4*>(sB + row * 128 + ((slot ^ (row & 7)) * 16)) = v;
            }
        }
        __syncthreads();
        #pragma unroll
        for (int k2 = 0; k2 < 2; ++k2) {
            bf16x8 a[2], b[5];
            #pragma unroll
            for (int rf = 0; rf < 2; ++rf) {
                int row = w * 32 + rf * 16 + (lane & 15);
                int off = (k2 * 64 + (lane >> 4) * 16) ^ ((row & 7) << 4);
                a[rf] = *reinterpret_cast<const bf16x8*>(sA + row * 128 + off);
            }
            #pragma unroll
            for (int cf = 0; cf < 5; ++cf) {
                int row = cf * 16 + (lane & 15);
                int off = (k2 * 64 + (lane >> 4) * 16) ^ ((row & 7) << 4);
                b[cf] = *reinterpret_cast<const bf16x8*>(sB + row * 128 + off);
            }
            #pragma unroll
            for (int rf = 0; rf < 2; ++rf)
                #pragma unroll
                for (int cf = 0; cf < 5; ++cf)
                    acc[rf][cf] = __builtin_amdgcn_mfma_f32_16x16x32_bf16(a[rf], b[cf], acc[rf][cf], 0, 0, 0);
        }
        __syncthreads();
    }
    #pragma unroll
    for (int cf = 0; cf < 5; ++cf) {
        int col = n0 + cf * 16 + (lane & 15);
        float bv = bias[col];
        #pragma unroll
        for (int rf = 0; rf < 2; ++rf)
            #pragma unroll
            for (int r = 0; r < 4; ++r) {
                int row = m0 + w * 32 + rf * 16 + (lane >> 4) * 4 + r;
                Cout[(size_t)row * VOCAB + col] = acc[rf][cf][r] + bv;
            }
    }
}

// ---------------------------------------------------------------------------
__global__ void finalize_hc(const float* __restrict__ hfin, const float* __restrict__ cfin,
                            float* __restrict__ out) {
    int i = blockIdx.x * 256 + threadIdx.x;       // 0..65535
    size_t base = (size_t)M_ROWS * VOCAB;
    if (i < BATCH * HIDDEN)
        out[base + i] = hfin[i];
    else
        out[base + i] = cfin[i - BATCH * HIDDEN];
}

extern "C" void kernel_launch(void* const* d_in, const int* in_sizes, int n_in,
                              void* d_out, int out_size, void* d_ws, size_t ws_size,
                              hipStream_t stream) {
    (void)in_sizes; (void)n_in; (void)out_size; (void)ws_size;
    const int*   input_ = (const int*)  d_in[0];
    const float* Emb    = (const float*)d_in[1];
    const float* Wxi    = (const float*)d_in[2];
    const float* Whi    = (const float*)d_in[3];
    const float* bi     = (const float*)d_in[4];
    const float* Wxf    = (const float*)d_in[5];
    const float* Whf    = (const float*)d_in[6];
    const float* bf_    = (const float*)d_in[7];
    const float* Wxc    = (const float*)d_in[8];
    const float* Whc    = (const float*)d_in[9];
    const float* bc     = (const float*)d_in[10];
    const float* Wxo    = (const float*)d_in[11];
    const float* Who    = (const float*)d_in[12];
    const float* bo     = (const float*)d_in[13];
    const float* W      = (const float*)d_in[14];
    const float* b      = (const float*)d_in[15];
    float* out = (float*)d_out;

    char* ws = (char*)d_ws;
    float*          xg   = (float*)         (ws);                 // 67,108,864
    unsigned short* hsbf = (unsigned short*)(ws +  67108864);     //  8,388,608
    unsigned short* Wtbf = (unsigned short*)(ws +  75497472);     // 10,240,000
    unsigned short* WhT  = (unsigned short*)(ws +  85737472);     //  2,097,152
    unsigned short* hbuf = (unsigned short*)(ws +  87834624);     //     65,536
    float*          hfin = (float*)         (ws +  87900160);     //    131,072
    float*          cbuf = (float*)         (ws +  88031232);     //    131,072
    unsigned*       bar  = (unsigned*)      (ws +  88162304);     //        512

    wt_convert<<<dim3(313, 16), dim3(32, 32), 0, stream>>>(W, Wtbf);
    wh_convert<<<dim3(16, 16, 4), dim3(32, 32), 0, stream>>>(Whi, Whf, Whc, Who, WhT);
    xproj<<<dim3(32, 64), 256, 0, stream>>>(input_, Emb, Wxi, Wxf, Wxc, Wxo,
                                            bi, bf_, bc, bo, xg);
    hipMemsetAsync(bar, 0, 512, stream);

    {
        const float* xg_c = xg;
        const unsigned short* WhT_c = WhT;
        unsigned short* hbuf_p = hbuf; unsigned short* hsbf_p = hsbf;
        float* hfin_p = hfin; float* cbuf_p = cbuf; unsigned* bar_p = bar;
        void* args[] = { (void*)&xg_c, (void*)&WhT_c, (void*)&hbuf_p, (void*)&hsbf_p,
                         (void*)&hfin_p, (void*)&cbuf_p, (void*)&bar_p };
        hipLaunchCooperativeKernel((void*)lstm_scan, dim3(NBLK), dim3(512), args, 0, stream);
    }

    out_proj<<<dim3(125, 64), 256, 0, stream>>>(hsbf, Wtbf, b, out);
    finalize_hc<<<256, 256, 0, stream>>>(hfin, cbuf, out);
}

// Round 5
// 865.003 us; speedup vs baseline: 11.3549x; 1.0446x over previous
//
#include <hip/hip_runtime.h>
#include <stdint.h>

#define T_STEPS 128
#define BATCH   64
#define EMBED   256
#define HIDDEN  512
#define VOCAB   10000
#define M_ROWS  (T_STEPS*BATCH)   // 8192
#define NGATE   (4*HIDDEN)        // 2048
#define NBLK    32                // lstm blocks

typedef __attribute__((ext_vector_type(2))) float  f32x2;
typedef __attribute__((ext_vector_type(4))) float  f32x4;
typedef __attribute__((ext_vector_type(4))) int    i32x4;
typedef __attribute__((ext_vector_type(8))) __bf16 bf16x8;

static __device__ __forceinline__ unsigned short f32_to_bf16(float f) {
    union { float f; uint32_t u; } v; v.f = f;
    uint32_t u = v.u;
    return (unsigned short)((u + 0x7FFFu + ((u >> 16) & 1u)) >> 16);  // RNE
}
static __device__ __forceinline__ float sigf(float x) {
    return 1.f / (1.f + __expf(-x));
}
static __device__ __forceinline__ float tanhfast(float x) {
    float e = __expf(2.f * fminf(fmaxf(x, -15.f), 15.f));
    return (e - 1.f) / (e + 1.f);
}

// ---------------------------------------------------------------------------
// Poison hsbf with 0xFFFFFFFF via sc0/sc1 stores (straight to IC, no L2
// lines anywhere). Sentinel = packed bf16 NaN pair, unreachable for h.
// ---------------------------------------------------------------------------
__global__ void poison_hsbf(unsigned* __restrict__ p) {
    size_t i = (size_t)blockIdx.x * 256 + threadIdx.x;   // 524288 threads x 16B
    i32x4 v = { -1, -1, -1, -1 };
    asm volatile("global_store_dwordx4 %0, %1, off sc0 sc1"
                 :: "v"((char*)p + i * 16), "v"(v) : "memory");
}

// ---------------------------------------------------------------------------
// W [512][10000] f32  ->  Wt [10000][512] bf16   (tiled transpose + convert)
// ---------------------------------------------------------------------------
__global__ void wt_convert(const float* __restrict__ W, unsigned short* __restrict__ Wt) {
    __shared__ float tile[32][33];
    int n0 = blockIdx.x * 32;
    int k0 = blockIdx.y * 32;
    int tx = threadIdx.x, ty = threadIdx.y;
    int n = n0 + tx;
    if (n < VOCAB) tile[ty][tx] = W[(size_t)(k0 + ty) * VOCAB + n];
    __syncthreads();
    int nn = n0 + ty;
    if (nn < VOCAB) Wt[(size_t)nn * HIDDEN + k0 + tx] = f32_to_bf16(tile[tx][ty]);
}

// ---------------------------------------------------------------------------
// Wh_g [512 k][512 n] f32 -> WhT [4][512 n][512 k] bf16
// ---------------------------------------------------------------------------
__global__ void wh_convert(const float* __restrict__ Whi, const float* __restrict__ Whf,
                           const float* __restrict__ Whc, const float* __restrict__ Who,
                           unsigned short* __restrict__ WhT) {
    __shared__ float tile[32][33];
    int g = blockIdx.z;
    const float* Wg = (g == 0) ? Whi : (g == 1) ? Whf : (g == 2) ? Whc : Who;
    int n0 = blockIdx.x * 32, k0 = blockIdx.y * 32;
    int tx = threadIdx.x, ty = threadIdx.y;
    tile[ty][tx] = Wg[(size_t)(k0 + ty) * HIDDEN + n0 + tx];
    __syncthreads();
    WhT[((size_t)g * HIDDEN + n0 + ty) * HIDDEN + k0 + tx] = f32_to_bf16(tile[tx][ty]);
}

// ---------------------------------------------------------------------------
// xg[m][g*512+hc] = embeddings[input_[m]] @ W_xg + b_g   (fp32 tiled GEMM)
// ---------------------------------------------------------------------------
__global__ __launch_bounds__(256) void xproj(
    const int* __restrict__ idx, const float* __restrict__ Emb,
    const float* __restrict__ Wxi, const float* __restrict__ Wxf,
    const float* __restrict__ Wxc, const float* __restrict__ Wxo,
    const float* __restrict__ bi,  const float* __restrict__ bf_,
    const float* __restrict__ bc,  const float* __restrict__ bo,
    float* __restrict__ xg)
{
    __shared__ float At[32][132];   // [k][m], padded
    __shared__ float Bt[32][68];    // [k][n], padded
    int cb = blockIdx.x;            // 0..31 (8 col-blocks per gate)
    int rb = blockIdx.y;            // 0..63
    int g  = cb >> 3;
    int hc0 = (cb & 7) * 64;
    const float* Wg = (g == 0) ? Wxi : (g == 1) ? Wxf : (g == 2) ? Wxc : Wxo;
    const float* bg = (g == 0) ? bi  : (g == 1) ? bf_ : (g == 2) ? bc  : bo;
    int m0 = rb * 128;
    int tid = threadIdx.x;
    int tr = tid >> 4, tc = tid & 15;
    float acc[8][4] = {};

    for (int kc = 0; kc < EMBED; kc += 32) {
        #pragma unroll
        for (int i = 0; i < 4; ++i) {
            int s = tid + i * 256;            // 0..1023
            int row = s >> 3, k4 = s & 7;
            int er = idx[m0 + row];
            f32x4 v = *reinterpret_cast<const f32x4*>(Emb + (size_t)er * EMBED + kc + k4 * 4);
            #pragma unroll
            for (int j = 0; j < 4; ++j) At[k4 * 4 + j][row] = v[j];
        }
        #pragma unroll
        for (int i = 0; i < 2; ++i) {
            int s = tid + i * 256;            // 0..511
            int k = s >> 4, c4 = s & 15;
            f32x4 v = *reinterpret_cast<const f32x4*>(Wg + (size_t)(kc + k) * HIDDEN + hc0 + c4 * 4);
            *reinterpret_cast<f32x4*>(&Bt[k][c4 * 4]) = v;
        }
        __syncthreads();
        #pragma unroll 8
        for (int k = 0; k < 32; ++k) {
            f32x4 a0 = *reinterpret_cast<const f32x4*>(&At[k][tr * 8]);
            f32x4 a1 = *reinterpret_cast<const f32x4*>(&At[k][tr * 8 + 4]);
            f32x4 b4 = *reinterpret_cast<const f32x4*>(&Bt[k][tc * 4]);
            float av[8] = {a0[0],a0[1],a0[2],a0[3],a1[0],a1[1],a1[2],a1[3]};
            #pragma unroll
            for (int i = 0; i < 8; ++i)
                #pragma unroll
                for (int j = 0; j < 4; ++j)
                    acc[i][j] += av[i] * b4[j];
        }
        __syncthreads();
    }
    f32x4 bb = *reinterpret_cast<const f32x4*>(bg + hc0 + tc * 4);
    #pragma unroll
    for (int i = 0; i < 8; ++i) {
        int row = m0 + tr * 8 + i;
        f32x4 o;
        #pragma unroll
        for (int j = 0; j < 4; ++j) o[j] = acc[i][j] + bb[j];
        *reinterpret_cast<f32x4*>(xg + (size_t)row * NGATE + g * HIDDEN + hc0 + tc * 4) = o;
    }
}

// ---------------------------------------------------------------------------
// Persistent LSTM scan, 32 blocks x 512 threads, NO barrier: data-flow sync.
// hsbf[t] (pre-poisoned 0xFFFFFFFF) is both the history buffer and the
// exchange medium; producers sc-store h, consumers sc-load + sentinel-poll.
// ---------------------------------------------------------------------------
__global__ __launch_bounds__(512) void lstm_scan(
    const float* __restrict__ xg,
    const unsigned short* __restrict__ WhT,   // [4][512][512] bf16
    unsigned short* hsbf,                     // [128][64][512] bf16 (poisoned)
    float* __restrict__ hfin, float* __restrict__ cfin)
{
    __shared__ __align__(16) unsigned char hstage[65536];  // 64 x 512 bf16, swizzled
    __shared__ float P_lds[4][64][17];                     // padded (bank)
    const int tid  = threadIdx.x;
    const int bx   = blockIdx.x;        // 0..31
    const int hc0  = bx * 16;
    const int lane = tid & 63, w = tid >> 6;
    const int wm   = w >> 2, wg = w & 3;

    // ---- preload Wh slice: wave (.,wg) lane l: col hc0+(l&15), 8 k per kstep
    bf16x8 breg[16];
    {
        const unsigned short* base =
            WhT + ((size_t)wg * HIDDEN + hc0 + (lane & 15)) * HIDDEN + (lane >> 4) * 8;
        #pragma unroll
        for (int ks = 0; ks < 16; ++ks)
            breg[ks] = *reinterpret_cast<const bf16x8*>(base + ks * 32);
    }

    // ---- update-thread mapping: thread -> (batch, hc pair)
    const int ub  = tid >> 3;          // 0..63
    const int uhp = tid & 7;           // 0..7
    const int uhc = hc0 + uhp * 2;
    float c0 = 0.f, c1 = 0.f;
    f32x2 xv[4];
    {
        const float* xrow = xg + (size_t)ub * NGATE + uhc;
        #pragma unroll
        for (int g = 0; g < 4; ++g)
            xv[g] = *reinterpret_cast<const f32x2*>(xrow + g * HIDDEN);
    }

    for (int t = 0; t < T_STEPS; ++t) {
        f32x4 acc0 = {0.f,0.f,0.f,0.f}, acc1 = {0.f,0.f,0.f,0.f};
        if (t > 0) {
            // poll-load h_{t-1} (64KB) from hsbf[t-1] via IC until no sentinel
            const char* hb = (const char*)hsbf + (size_t)(t - 1) * 65536;
            i32x4 r0, r1, r2, r3, r4, r5, r6, r7;
            for (;;) {
#define LDIC(R, I) asm volatile("global_load_dwordx4 %0, %1, off sc0 sc1" \
        : "=v"(R) : "v"(hb + (size_t)((I) * 512 + tid) * 16));
                LDIC(r0, 0) LDIC(r1, 1) LDIC(r2, 2) LDIC(r3, 3)
                LDIC(r4, 4) LDIC(r5, 5) LDIC(r6, 6) LDIC(r7, 7)
#undef LDIC
                // register-tied waitcnt: compare below cannot be hoisted above
                asm volatile("s_waitcnt vmcnt(0)"
                    : "+v"(r0), "+v"(r1), "+v"(r2), "+v"(r3),
                      "+v"(r4), "+v"(r5), "+v"(r6), "+v"(r7));
                unsigned mx = 0u;
#define CHK(R) { mx = (mx > (unsigned)R[0]) ? mx : (unsigned)R[0]; \
                 mx = (mx > (unsigned)R[1]) ? mx : (unsigned)R[1]; \
                 mx = (mx > (unsigned)R[2]) ? mx : (unsigned)R[2]; \
                 mx = (mx > (unsigned)R[3]) ? mx : (unsigned)R[3]; }
                CHK(r0) CHK(r1) CHK(r2) CHK(r3) CHK(r4) CHK(r5) CHK(r6) CHK(r7)
#undef CHK
                if (mx != 0xFFFFFFFFu) break;     // max == -1  <=>  some sentinel
                __builtin_amdgcn_s_sleep(1);
            }
            __builtin_amdgcn_sched_barrier(0);
#define STLDS(R, I) { int s16 = (I) * 512 + tid; int row = s16 >> 6, sl = s16 & 63; \
        *reinterpret_cast<i32x4*>(hstage + row * 1024 + ((sl ^ (row & 7)) << 4)) = R; }
            STLDS(r0, 0) STLDS(r1, 1) STLDS(r2, 2) STLDS(r3, 3)
            STLDS(r4, 4) STLDS(r5, 5) STLDS(r6, 6) STLDS(r7, 7)
#undef STLDS
            __syncthreads();                       // SYNC_A
            const int r0r = wm * 32 + (lane & 15);
            const int r1r = r0r + 16;
            #pragma unroll
            for (int ks = 0; ks < 16; ++ks) {
                int sl = ks * 4 + (lane >> 4);
                bf16x8 a0 = *reinterpret_cast<const bf16x8*>(
                    hstage + r0r * 1024 + ((sl ^ (r0r & 7)) << 4));
                bf16x8 a1 = *reinterpret_cast<const bf16x8*>(
                    hstage + r1r * 1024 + ((sl ^ (r1r & 7)) << 4));
                acc0 = __builtin_amdgcn_mfma_f32_16x16x32_bf16(a0, breg[ks], acc0, 0, 0, 0);
                acc1 = __builtin_amdgcn_mfma_f32_16x16x32_bf16(a1, breg[ks], acc1, 0, 0, 0);
            }
        }
        // ---- exchange preacts via LDS (C layout: col=lane&15, row=(lane>>4)*4+r)
        {
            int colr = lane & 15, rowb = (lane >> 4) * 4;
            #pragma unroll
            for (int r = 0; r < 4; ++r) {
                P_lds[wg][wm * 32 + rowb + r][colr]      = acc0[r];
                P_lds[wg][wm * 32 + 16 + rowb + r][colr] = acc1[r];
            }
        }
        __syncthreads();                           // SYNC_B
        // ---- cell update: 2 (b,hc) per thread
        {
            int hp2 = uhp * 2;
            float pi0 = P_lds[0][ub][hp2] + xv[0][0], pi1 = P_lds[0][ub][hp2+1] + xv[0][1];
            float pf0 = P_lds[1][ub][hp2] + xv[1][0], pf1 = P_lds[1][ub][hp2+1] + xv[1][1];
            float pg0 = P_lds[2][ub][hp2] + xv[2][0], pg1 = P_lds[2][ub][hp2+1] + xv[2][1];
            float po0 = P_lds[3][ub][hp2] + xv[3][0], po1 = P_lds[3][ub][hp2+1] + xv[3][1];
            float i0 = sigf(pi0), i1 = sigf(pi1);
            float f0 = sigf(pf0), f1 = sigf(pf1);
            float g0 = tanhfast(pg0), g1 = tanhfast(pg1);
            float o0 = sigf(po0), o1 = sigf(po1);
            c0 = f0 * c0 + i0 * g0;
            c1 = f1 * c1 + i1 * g1;
            float h0 = o0 * tanhfast(c0);
            float h1 = o1 * tanhfast(c1);
            unsigned hp = ((unsigned)f32_to_bf16(h1) << 16) | (unsigned)f32_to_bf16(h0);
            // h store: straight to IC; this IS the publication (no flag/barrier)
            {
                unsigned* dst = reinterpret_cast<unsigned*>(hsbf)
                                + (size_t)(t * BATCH + ub) * 256 + (uhc >> 1);
                asm volatile("global_store_dword %0, %1, off sc0 sc1"
                             :: "v"(dst), "v"(hp) : "memory");
            }
            if (t == T_STEPS - 1) {
                f32x2 hv = { h0, h1 };
                *reinterpret_cast<f32x2*>(hfin + (size_t)ub * HIDDEN + uhc) = hv;
            }
            // prefetch next step's x-gate row AFTER the h store (off the
            // publication critical path; overlaps next poll)
            if (t + 1 < T_STEPS) {
                const float* xrow = xg + (size_t)((t + 1) * BATCH + ub) * NGATE + uhc;
                #pragma unroll
                for (int g = 0; g < 4; ++g)
                    xv[g] = *reinterpret_cast<const f32x2*>(xrow + g * HIDDEN);
            }
        }
        // no barrier: next iteration's poll is the synchronization
    }
    // ---- final c
    {
        f32x2 cv = { c0, c1 };
        *reinterpret_cast<f32x2*>(cfin + (size_t)ub * HIDDEN + uhc) = cv;
    }
}

// ---------------------------------------------------------------------------
// out = hs_bf16 [8192,512] @ W_bf16^T [10000,512] + b   (bf16 MFMA, f32 acc)
// ---------------------------------------------------------------------------
__global__ __launch_bounds__(256) void out_proj(
    const unsigned short* __restrict__ Abf,   // [8192][512]
    const unsigned short* __restrict__ Btbf,  // [10000][512]
    const float* __restrict__ bias,           // [10000]
    float* __restrict__ Cout)                 // [8192][10000] f32
{
    __shared__ __align__(16) char sA[128 * 128];  // 128 rows x 64 bf16
    __shared__ __align__(16) char sB[80 * 128];   // 80 rows x 64 bf16
    int n0 = blockIdx.x * 80;
    int m0 = blockIdx.y * 128;
    int tid = threadIdx.x;
    int w = tid >> 6, lane = tid & 63;
    f32x4 acc[2][5] = {};

    for (int kc = 0; kc < 8; ++kc) {
        int k0 = kc * 64;
        #pragma unroll
        for (int i = 0; i < 4; ++i) {                  // A: 1024 16B slots
            int s = tid + i * 256;
            int row = s >> 3, slot = s & 7;
            i32x4 v = *reinterpret_cast<const i32x4*>(Abf + (size_t)(m0 + row) * HIDDEN + k0 + slot * 8);
            *reinterpret_cast<i32x4*>(sA + row * 128 + ((slot ^ (row & 7)) * 16)) = v;
        }
        #pragma unroll
        for (int i = 0; i < 3; ++i) {                  // B: 640 slots
            int s = tid + i * 256;
            if (s < 640) {
                int row = s >> 3, slot = s & 7;
                i32x4 v = *reinterpret_cast<const i32x4*>(Btbf + (size_t)(n0 + row) * HIDDEN + k0 + slot * 8);
                *reinterpret_cast<i32x4*>(sB + row * 128 + ((slot ^ (row & 7)) * 16)) = v;
            }
        }
        __syncthreads();
        #pragma unroll
        for (int k2 = 0; k2 < 2; ++k2) {
            bf16x8 a[2], b[5];
            #pragma unroll
            for (int rf = 0; rf < 2; ++rf) {
                int row = w * 32 + rf * 16 + (lane & 15);
                int off = (k2 * 64 + (lane >> 4) * 16) ^ ((row & 7) << 4);
                a[rf] = *reinterpret_cast<const bf16x8*>(sA + row * 128 + off);
            }
            #pragma unroll
            for (int cf = 0; cf < 5; ++cf) {
                int row = cf * 16 + (lane & 15);
                int off = (k2 * 64 + (lane >> 4) * 16) ^ ((row & 7) << 4);
                b[cf] = *reinterpret_cast<const bf16x8*>(sB + row * 128 + off);
            }
            #pragma unroll
            for (int rf = 0; rf < 2; ++rf)
                #pragma unroll
                for (int cf = 0; cf < 5; ++cf)
                    acc[rf][cf] = __builtin_amdgcn_mfma_f32_16x16x32_bf16(a[rf], b[cf], acc[rf][cf], 0, 0, 0);
        }
        __syncthreads();
    }
    #pragma unroll
    for (int cf = 0; cf < 5; ++cf) {
        int col = n0 + cf * 16 + (lane & 15);
        float bv = bias[col];
        #pragma unroll
        for (int rf = 0; rf < 2; ++rf)
            #pragma unroll
            for (int r = 0; r < 4; ++r) {
                int row = m0 + w * 32 + rf * 16 + (lane >> 4) * 4 + r;
                Cout[(size_t)row * VOCAB + col] = acc[rf][cf][r] + bv;
            }
    }
}

// ---------------------------------------------------------------------------
__global__ void finalize_hc(const float* __restrict__ hfin, const float* __restrict__ cfin,
                            float* __restrict__ out) {
    int i = blockIdx.x * 256 + threadIdx.x;       // 0..65535
    size_t base = (size_t)M_ROWS * VOCAB;
    if (i < BATCH * HIDDEN)
        out[base + i] = hfin[i];
    else
        out[base + i] = cfin[i - BATCH * HIDDEN];
}

extern "C" void kernel_launch(void* const* d_in, const int* in_sizes, int n_in,
                              void* d_out, int out_size, void* d_ws, size_t ws_size,
                              hipStream_t stream) {
    (void)in_sizes; (void)n_in; (void)out_size; (void)ws_size;
    const int*   input_ = (const int*)  d_in[0];
    const float* Emb    = (const float*)d_in[1];
    const float* Wxi    = (const float*)d_in[2];
    const float* Whi    = (const float*)d_in[3];
    const float* bi     = (const float*)d_in[4];
    const float* Wxf    = (const float*)d_in[5];
    const float* Whf    = (const float*)d_in[6];
    const float* bf_    = (const float*)d_in[7];
    const float* Wxc    = (const float*)d_in[8];
    const float* Whc    = (const float*)d_in[9];
    const float* bc     = (const float*)d_in[10];
    const float* Wxo    = (const float*)d_in[11];
    const float* Who    = (const float*)d_in[12];
    const float* bo     = (const float*)d_in[13];
    const float* W      = (const float*)d_in[14];
    const float* b      = (const float*)d_in[15];
    float* out = (float*)d_out;

    char* ws = (char*)d_ws;
    float*          xg   = (float*)         (ws);                 // 67,108,864
    unsigned short* hsbf = (unsigned short*)(ws +  67108864);     //  8,388,608
    unsigned short* Wtbf = (unsigned short*)(ws +  75497472);     // 10,240,000
    unsigned short* WhT  = (unsigned short*)(ws +  85737472);     //  2,097,152
    float*          hfin = (float*)         (ws +  87834624);     //    131,072
    float*          cbuf = (float*)         (ws +  87965696);     //    131,072

    poison_hsbf<<<2048, 256, 0, stream>>>((unsigned*)hsbf);
    wt_convert<<<dim3(313, 16), dim3(32, 32), 0, stream>>>(W, Wtbf);
    wh_convert<<<dim3(16, 16, 4), dim3(32, 32), 0, stream>>>(Whi, Whf, Whc, Who, WhT);
    xproj<<<dim3(32, 64), 256, 0, stream>>>(input_, Emb, Wxi, Wxf, Wxc, Wxo,
                                            bi, bf_, bc, bo, xg);

    {
        const float* xg_c = xg;
        const unsigned short* WhT_c = WhT;
        unsigned short* hsbf_p = hsbf;
        float* hfin_p = hfin; float* cbuf_p = cbuf;
        void* args[] = { (void*)&xg_c, (void*)&WhT_c, (void*)&hsbf_p,
                         (void*)&hfin_p, (void*)&cbuf_p };
        hipLaunchCooperativeKernel((void*)lstm_scan, dim3(NBLK), dim3(512), args, 0, stream);
    }

    out_proj<<<dim3(125, 64), 256, 0, stream>>>(hsbf, Wtbf, b, out);
    finalize_hc<<<256, 256, 0, stream>>>(hfin, cbuf, out);
}